// Round 25
// baseline (282.197 us; speedup 1.0000x reference)
//
#include <hip/hip_runtime.h>
#include <hip/hip_bf16.h>
#include <stdint.h>

// ---------------------------------------------------------------------------
// ChebConv with attention + per-(t,k) dropout, MI355X bf16 MFMA implementation
// out[b,t,u,o] = relu( sum_k M[t,k] @ (x[b,t] @ Theta[k]) )
// mask = threefry2x32 partitionable, key(42), bits = x0^x1   (verified R0)
// B=32 T=12 V=1000(pad 1024) F=O=64 K=3
// ws: Mf frag-order [36<<20] bf16 (75.5MB) | xt row-major [12][2048][1024]
//
// R25: R24 base (hybrid: A direct from frag-order Mf, B via LDS dbuf, XOR
// swizzle, fused stage-2 -- 272.9us, cheb_main 195us @ 36.5% MfmaUtil stable)
// with ONE change: B buffers widened to two 64-chunks (32KB each, 64KB dbuf)
// -> barrier count in the K-loop halves 16 -> 8, 96 MFMA between barriers.
// Isolates the per-barrier convergence+ramp tax, the last unprobed term.
// NT stores reverted to normal (R22/R24: timing-neutral, write-amplifying).
// ---------------------------------------------------------------------------

typedef __attribute__((ext_vector_type(8))) short short8;
typedef __attribute__((ext_vector_type(4))) float f32x4;

__device__ __forceinline__ ushort f2bf(float f) {
  __hip_bfloat16 h = __float2bfloat16(f);
  return *reinterpret_cast<ushort*>(&h);
}

__device__ __forceinline__ void threefry2x32(uint32_t c0, uint32_t c1,
                                             uint32_t& o0, uint32_t& o1) {
  const uint32_t ks0 = 0u;
  const uint32_t ks1 = 42u;
  const uint32_t ks2 = ks0 ^ ks1 ^ 0x1BD11BDAu;
  uint32_t x0 = c0 + ks0;
  uint32_t x1 = c1 + ks1;
#define TFR(r) { x0 += x1; x1 = (x1 << (r)) | (x1 >> (32 - (r))); x1 ^= x0; }
  TFR(13) TFR(15) TFR(26) TFR(6)
  x0 += ks1; x1 += ks2 + 1u;
  TFR(17) TFR(29) TFR(16) TFR(24)
  x0 += ks2; x1 += ks0 + 2u;
  TFR(13) TFR(15) TFR(26) TFR(6)
  x0 += ks0; x1 += ks1 + 3u;
  TFR(17) TFR(29) TFR(16) TFR(24)
  x0 += ks1; x1 += ks2 + 4u;
  TFR(13) TFR(15) TFR(26) TFR(6)
  x0 += ks2; x1 += ks0 + 5u;
#undef TFR
  o0 = x0; o1 = x1;
}

// ---------------------------------------------------------------------------
// Kernel 1 (fused prep): blocks [0,6144) = transpose_x (HBM-bound),
// [6144,153600) = build_m in FRAGMENT order (VALU-bound) -- pipes overlap.
// Frag order (R11/R16-verified): elem = (((tk*64+u16)*16+vc)*2+ks)*512
//   + lane*8 + j;  u = u16*16+(lane&15), v = vc*64+ks*32+(lane>>4)*8+j.
// ---------------------------------------------------------------------------
__global__ void prep(const float* __restrict__ x,
                     const float* __restrict__ Att,
                     const float* __restrict__ cheb,
                     ushort* __restrict__ Mf,
                     ushort* __restrict__ xtw) {
  __shared__ float lt[64][65];
  const int bid = blockIdx.x;
  const int tid = threadIdx.x;

  if (bid >= 6144) {
    // ---- build_m role: masked M in MFMA-fragment order ----
    const uint32_t idx = (uint32_t)(bid - 6144) * 256u + tid;
    const uint32_t j = idx & 7u;
    const uint32_t lane = (idx >> 3) & 63u;
    const uint32_t ks = (idx >> 9) & 1u;
    const uint32_t c = (idx >> 10) & 15u;
    const uint32_t u16 = (idx >> 14) & 63u;
    const uint32_t tk = idx >> 20;
    const uint32_t up = u16 * 16u + (lane & 15u);
    const uint32_t vp = c * 64u + ks * 32u + (lane >> 4) * 8u + j;
    float val = 0.f;
    if ((vp < 1000u) & (up < 1000u)) {
      const uint32_t flat = (tk * 1000u + up) * 1000u + vp;
      uint32_t o0, o1;
      threefry2x32(0u, flat, o0, o1);
      const uint32_t bits = o0 ^ o1;
      const float u = __uint_as_float((bits >> 9) | 0x3f800000u) - 1.0f;
      if (u < 0.4f) {
        val = cheb[(tk % 3u) * 1000000u + up * 1000u + vp] *
              Att[up * 1000u + vp] * 2.5f;
      }
    }
    Mf[idx] = f2bf(val);
    return;
  }

  // ---- transpose role: xt[t][n=b*64+f][v pad 1024] <- x[b][t][v][f] ----
  const int r = bid;
  const int vc = r & 15, t = (r >> 4) % 12, b = r / 192;
  const int v0 = vc * 64;
#pragma unroll
  for (int i = 0; i < 4; ++i) {
    const int c = i * 256 + tid;
    const int vi = c >> 4, f4 = c & 15;
    float4 q = make_float4(0.f, 0.f, 0.f, 0.f);
    if (v0 + vi < 1000)
      q = *(const float4*)(x + ((((size_t)b * 12 + t) * 1000 + v0 + vi) << 6) + f4 * 4);
    lt[f4 * 4 + 0][vi] = q.x;
    lt[f4 * 4 + 1][vi] = q.y;
    lt[f4 * 4 + 2][vi] = q.z;
    lt[f4 * 4 + 3][vi] = q.w;
  }
  __syncthreads();
  const int f = tid >> 2, g = tid & 3;
  alignas(16) ushort tmp[16];
#pragma unroll
  for (int j = 0; j < 16; ++j) tmp[j] = f2bf(lt[f][g * 16 + j]);
  const size_t base = ((size_t)(t * 2048 + b * 64 + f)) << 10;
  *(uint4*)(xtw + base + v0 + g * 16)     = *(const uint4*)&tmp[0];
  *(uint4*)(xtw + base + v0 + g * 16 + 8) = *(const uint4*)&tmp[8];
}

// ---------------------------------------------------------------------------
// Kernel 2: main fused GEMM, hybrid operand paths.
// 256 thr (4 waves, 2x2), block 64u x 128n per t, wave tile 32u x 64n.
// A = 12 frag loads per 64-chunk direct from Mf (coalesced 1KB, L2-hot);
// B = LDS dbuf of DOUBLE-WIDE buffers (2 chunks = 32KB each; 64KB total),
//     XOR content swizzle (verified), issue-early named-reg prefetch,
//     ONE barrier per TWO chunks (8 barriers total in the K-loop).
// 96 MFMA between barriers into pacc[3] (AGPR).
// Stage 2 (k unrolled): pacc[k] -> sP -> oacc += P @ ThetaT[k].
// Grid 3072 1D, XCD-bijective, ut-fastest (A panels L2-hot per XCD).
// ---------------------------------------------------------------------------
#define LDT 72
#define MFMA(a, b, c) __builtin_amdgcn_mfma_f32_16x16x32_bf16((a), (b), (c), 0, 0, 0)

// load chunks VC and VC+1 of B into pB0..pB7 (issue-early)
#define LOADB2(VC)                                                            \
  do {                                                                        \
    const size_t c0_ = (size_t)(VC) * 64;                                     \
    const size_t c1_ = (size_t)(VC + 1) * 64;                                 \
    pB0 = *(const uint4*)(xt + bS0 + c0_);                                    \
    pB1 = *(const uint4*)(xt + bS1 + c0_);                                    \
    pB2 = *(const uint4*)(xt + bS2 + c0_);                                    \
    pB3 = *(const uint4*)(xt + bS3 + c0_);                                    \
    pB4 = *(const uint4*)(xt + bS0 + c1_);                                    \
    pB5 = *(const uint4*)(xt + bS1 + c1_);                                    \
    pB6 = *(const uint4*)(xt + bS2 + c1_);                                    \
    pB7 = *(const uint4*)(xt + bS3 + c1_);                                    \
  } while (0)

// commit pB0..pB7 into double-wide buffer BP (slab0 | slab1 at +8192)
#define WRITEB2(BP)                                                           \
  do {                                                                        \
    *(uint4*)&(BP)[(tid) * 8]               = pB0;                            \
    *(uint4*)&(BP)[(256 + tid) * 8]         = pB1;                            \
    *(uint4*)&(BP)[(512 + tid) * 8]         = pB2;                            \
    *(uint4*)&(BP)[(768 + tid) * 8]         = pB3;                            \
    *(uint4*)&(BP)[8192 + (tid) * 8]        = pB4;                            \
    *(uint4*)&(BP)[8192 + (256 + tid) * 8]  = pB5;                            \
    *(uint4*)&(BP)[8192 + (512 + tid) * 8]  = pB6;                            \
    *(uint4*)&(BP)[8192 + (768 + tid) * 8]  = pB7;                            \
  } while (0)

#define LOADA(VC)                                                             \
  do {                                                                        \
    const size_t co_ = (size_t)(VC) << 10;                                    \
    _Pragma("unroll")                                                         \
    for (int k = 0; k < 3; ++k)                                               \
      _Pragma("unroll")                                                       \
      for (int mi = 0; mi < 2; ++mi)                                          \
        _Pragma("unroll")                                                     \
        for (int ks = 0; ks < 2; ++ks)                                        \
          a[k][mi][ks] = *(const short8*)(Mf + fA[k][mi] + co_ +              \
                                          ((size_t)ks << 9));                 \
  } while (0)

// one 64-chunk of MFMA against B slab SP (48 MFMA)
#define BURST(SP)                                                             \
  do {                                                                        \
    _Pragma("unroll")                                                         \
    for (int ks = 0; ks < 2; ++ks) {                                          \
      const int cs_ = (((ks * 4 + quad) ^ rsw)) << 3;                         \
      short8 bv[4];                                                           \
      _Pragma("unroll")                                                       \
      for (int ni = 0; ni < 4; ++ni)                                          \
        bv[ni] = *(const short8*)&(SP)[(wn * 64 + ni * 16 + l15) * 64 + cs_]; \
      _Pragma("unroll")                                                       \
      for (int k = 0; k < 3; ++k)                                             \
        _Pragma("unroll")                                                     \
        for (int mi = 0; mi < 2; ++mi)                                        \
          _Pragma("unroll")                                                   \
          for (int ni = 0; ni < 4; ++ni)                                      \
            pacc[k][mi][ni] = MFMA(a[k][mi][ks], bv[ni], pacc[k][mi][ni]);    \
    }                                                                         \
  } while (0)

__global__ __launch_bounds__(256, 2)
void cheb_main(const ushort* __restrict__ Mf, const ushort* __restrict__ xt,
               const float* __restrict__ Theta, float* __restrict__ out) {
  __shared__ __align__(16) ushort smem[32768];  // 64KB: buf0 | buf1 (32KB ea)
  const int tid = threadIdx.x;
  const int lane = tid & 63;
  const int w = tid >> 6;              // wave 0..3
  const int wu = w >> 1, wn = w & 1;   // wave tile: u = wu*32, n = wn*64
  const int quad = lane >> 4, l15 = lane & 15;
  const int rsw = l15 & 7;

  ushort* buf0 = smem;
  ushort* buf1 = smem + 16384;

  // XCD-bijective decode (3072 % 8 == 0), ut-fastest within each XCD chunk
  const int bid = blockIdx.x;
  const int swz = (bid & 7) * 384 + (bid >> 3);
  const int ut = swz & 15;
  const int g = swz >> 4;              // 0..191
  const int nt = g & 15;
  const int t = g >> 4;                // 0..11
  const int u0 = ut * 64, n0 = nt * 128;

  // A fragment bases (frag-order Mf): u16 = ut*4 + wu*2 + mi
  size_t fA[3][2];
#pragma unroll
  for (int k = 0; k < 3; ++k)
#pragma unroll
    for (int mi = 0; mi < 2; ++mi)
      fA[k][mi] = (((size_t)((t * 3 + k) * 64 + ut * 4 + wu * 2 + mi)) << 14)
                  + (size_t)lane * 8;

  // B staging sources (xt row-major, XOR content pre-swizzle) -- verified
  const size_t xrow0 = (size_t)(t * 2048 + n0);
  const int rB0 = tid >> 3,         cB0 = (tid & 7) ^ (rB0 & 7);
  const int rB1 = (256 + tid) >> 3, cB1 = (tid & 7) ^ (rB1 & 7);
  const int rB2 = (512 + tid) >> 3, cB2 = (tid & 7) ^ (rB2 & 7);
  const int rB3 = (768 + tid) >> 3, cB3 = (tid & 7) ^ (rB3 & 7);
  const size_t bS0 = ((xrow0 + rB0) << 10) + cB0 * 8;
  const size_t bS1 = ((xrow0 + rB1) << 10) + cB1 * 8;
  const size_t bS2 = ((xrow0 + rB2) << 10) + cB2 * 8;
  const size_t bS3 = ((xrow0 + rB3) << 10) + cB3 * 8;

  f32x4 pacc[3][2][4];
#pragma unroll
  for (int k = 0; k < 3; ++k)
#pragma unroll
    for (int i = 0; i < 2; ++i)
#pragma unroll
      for (int j = 0; j < 4; ++j) pacc[k][i][j] = f32x4{0.f, 0.f, 0.f, 0.f};

  short8 a[3][2][2];
  uint4 pB0, pB1, pB2, pB3, pB4, pB5, pB6, pB7;

  // prologue: B chunks 0,1 -> buf0
  LOADB2(0);
  WRITEB2(buf0);
  __syncthreads();

  // main K loop: 16 chunks in 8 buffer-phases, ONE barrier per phase
#pragma unroll 1
  for (int it = 0; it < 4; ++it) {
    const int c = it * 4;
    // phase A: buf0 holds chunks c, c+1; prefetch c+2,c+3 -> buf1
    if (c + 2 < 16) LOADB2(c + 2);
    LOADA(c);
    __builtin_amdgcn_s_setprio(1);
    BURST(buf0);
    __builtin_amdgcn_s_setprio(0);
    LOADA(c + 1);
    __builtin_amdgcn_s_setprio(1);
    BURST(buf0 + 8192);
    __builtin_amdgcn_s_setprio(0);
    if (c + 2 < 16) WRITEB2(buf1);
    __syncthreads();
    // phase B: buf1 holds chunks c+2, c+3; prefetch c+4,c+5 -> buf0
    if (c + 4 < 16) LOADB2(c + 4);
    LOADA(c + 2);
    __builtin_amdgcn_s_setprio(1);
    BURST(buf1);
    __builtin_amdgcn_s_setprio(0);
    LOADA(c + 3);
    __builtin_amdgcn_s_setprio(1);
    BURST(buf1 + 8192);
    __builtin_amdgcn_s_setprio(0);
    if (c + 4 < 16) WRITEB2(buf0);
    __syncthreads();
  }

  // ---- stage 2: oacc += P_k @ ThetaT[k], k fully unrolled (verified) ----
  ushort* sP  = smem + w * 2304;       // 32 x 72, wave-local
  ushort* sTh = smem + 9216;           // 64 x 72  (13824 <= 32768)
  f32x4 oacc[2][4];
#pragma unroll
  for (int i = 0; i < 2; ++i)
#pragma unroll
    for (int j = 0; j < 4; ++j) oacc[i][j] = f32x4{0.f, 0.f, 0.f, 0.f};

#pragma unroll
  for (int k = 0; k < 3; ++k) {
    __syncthreads();  // prev readers done
#pragma unroll
    for (int mi = 0; mi < 2; ++mi)
#pragma unroll
      for (int ni = 0; ni < 4; ++ni)
#pragma unroll
        for (int r = 0; r < 4; ++r)
          sP[(mi * 16 + quad * 4 + r) * LDT + ni * 16 + l15] = f2bf(pacc[k][mi][ni][r]);
    for (int e = tid; e < 4096; e += 256) {
      const int f = e >> 6, o = e & 63;
      sTh[o * LDT + f] = f2bf(Theta[k * 4096 + e]);
    }
    __syncthreads();
#pragma unroll
    for (int ks = 0; ks < 2; ++ks) {
      short8 a2[2], b2[4];
#pragma unroll
      for (int mi = 0; mi < 2; ++mi)
        a2[mi] = *(const short8*)&sP[(mi * 16 + l15) * LDT + ks * 32 + quad * 8];
#pragma unroll
      for (int ni = 0; ni < 4; ++ni)
        b2[ni] = *(const short8*)&sTh[(ni * 16 + l15) * LDT + ks * 32 + quad * 8];
#pragma unroll
      for (int mi = 0; mi < 2; ++mi)
#pragma unroll
        for (int ni = 0; ni < 4; ++ni)
          oacc[mi][ni] = MFMA(a2[mi], b2[ni], oacc[mi][ni]);
    }
  }

  // ---- epilogue: relu + f32 store ----
#pragma unroll
  for (int mi = 0; mi < 2; ++mi) {
    const int u_base = u0 + wu * 32 + mi * 16 + quad * 4;
#pragma unroll
    for (int ni = 0; ni < 4; ++ni) {
      const int n = n0 + wn * 64 + ni * 16 + l15;
      const int b = n >> 6, oo = n & 63;
      float* op = out + (((size_t)b * 12 + t) * 1000) * 64 + oo;
#pragma unroll
      for (int r = 0; r < 4; ++r) {
        const int u = u_base + r;
        if (u < 1000) op[(size_t)u * 64] = fmaxf(oacc[mi][ni][r], 0.f);
      }
    }
  }
}

// ---------------------------------------------------------------------------
extern "C" void kernel_launch(void* const* d_in, const int* in_sizes, int n_in,
                              void* d_out, int out_size, void* d_ws, size_t ws_size,
                              hipStream_t stream) {
  const float* x     = (const float*)d_in[0];
  const float* Att   = (const float*)d_in[1];
  const float* cheb  = (const float*)d_in[2];
  const float* Theta = (const float*)d_in[3];
  float* out = (float*)d_out;

  ushort* Mf  = (ushort*)d_ws;                 // 36*1024*1024 bf16, frag order
  ushort* xtw = Mf + 37748736ull;              // 12*2048*1024 bf16 row-major
  // requires ws_size >= 125,829,120 bytes (proven budget)

  prep<<<153600, 256, 0, stream>>>(x, Att, cheb, Mf, xtw);
  cheb_main<<<3072, 256, 0, stream>>>(Mf, xtw, Theta, out);
}

// Round 26
// 272.043 us; speedup vs baseline: 1.0373x; 1.0373x over previous
//
#include <hip/hip_runtime.h>
#include <hip/hip_bf16.h>
#include <stdint.h>

// ---------------------------------------------------------------------------
// ChebConv with attention + per-(t,k) dropout, MI355X bf16 MFMA implementation
// out[b,t,u,o] = relu( sum_k M[t,k] @ (x[b,t] @ Theta[k]) )
// mask = threefry2x32 partitionable, key(42), bits = x0^x1   (verified R0)
// B=32 T=12 V=1000(pad 1024) F=O=64 K=3
// ws: Mf frag-order [36<<20] bf16 (75.5MB) | xt row-major [12][2048][1024]
//
// FINAL (session optimum, 271.7-272.9us measured, 4x reproduced):
// Fused prep (transpose + frag-order build_m, pipe-overlapped) + hybrid
// cheb_main: A direct from fragment-order Mf (per-wave coalesced 1KB loads,
// L1-broadcast across wn-pairs), B via LDS dbuf (2x16KB, 1 barrier/chunk,
// XOR content swizzle), pacc[3] in AGPRs, fused stage-2 (P_k @ ThetaT[k]).
// Twelve structural variants (R8-R25) pin the GEMM at 193-262us / MfmaUtil
// 25-37% -- the documented 2-phase schedule-family ceiling (m233/m97-class);
// this hybrid is the family minimum. The 8-phase escape requires the gl_lds
// prerequisite that failed in R2 plus a full schedule rewrite.
// ---------------------------------------------------------------------------

typedef __attribute__((ext_vector_type(8))) short short8;
typedef __attribute__((ext_vector_type(4))) float f32x4;

__device__ __forceinline__ ushort f2bf(float f) {
  __hip_bfloat16 h = __float2bfloat16(f);
  return *reinterpret_cast<ushort*>(&h);
}

__device__ __forceinline__ void threefry2x32(uint32_t c0, uint32_t c1,
                                             uint32_t& o0, uint32_t& o1) {
  const uint32_t ks0 = 0u;
  const uint32_t ks1 = 42u;
  const uint32_t ks2 = ks0 ^ ks1 ^ 0x1BD11BDAu;
  uint32_t x0 = c0 + ks0;
  uint32_t x1 = c1 + ks1;
#define TFR(r) { x0 += x1; x1 = (x1 << (r)) | (x1 >> (32 - (r))); x1 ^= x0; }
  TFR(13) TFR(15) TFR(26) TFR(6)
  x0 += ks1; x1 += ks2 + 1u;
  TFR(17) TFR(29) TFR(16) TFR(24)
  x0 += ks2; x1 += ks0 + 2u;
  TFR(13) TFR(15) TFR(26) TFR(6)
  x0 += ks0; x1 += ks1 + 3u;
  TFR(17) TFR(29) TFR(16) TFR(24)
  x0 += ks1; x1 += ks2 + 4u;
  TFR(13) TFR(15) TFR(26) TFR(6)
  x0 += ks2; x1 += ks0 + 5u;
#undef TFR
  o0 = x0; o1 = x1;
}

// ---------------------------------------------------------------------------
// Kernel 1 (fused prep): blocks [0,6144) = transpose_x (HBM-bound),
// [6144,153600) = build_m in FRAGMENT order (VALU-bound) -- pipes overlap.
// Frag order (R11/R16-verified): elem = (((tk*64+u16)*16+vc)*2+ks)*512
//   + lane*8 + j;  u = u16*16+(lane&15), v = vc*64+ks*32+(lane>>4)*8+j.
// ---------------------------------------------------------------------------
__global__ void prep(const float* __restrict__ x,
                     const float* __restrict__ Att,
                     const float* __restrict__ cheb,
                     ushort* __restrict__ Mf,
                     ushort* __restrict__ xtw) {
  __shared__ float lt[64][65];
  const int bid = blockIdx.x;
  const int tid = threadIdx.x;

  if (bid >= 6144) {
    // ---- build_m role: masked M in MFMA-fragment order ----
    const uint32_t idx = (uint32_t)(bid - 6144) * 256u + tid;
    const uint32_t j = idx & 7u;
    const uint32_t lane = (idx >> 3) & 63u;
    const uint32_t ks = (idx >> 9) & 1u;
    const uint32_t c = (idx >> 10) & 15u;
    const uint32_t u16 = (idx >> 14) & 63u;
    const uint32_t tk = idx >> 20;
    const uint32_t up = u16 * 16u + (lane & 15u);
    const uint32_t vp = c * 64u + ks * 32u + (lane >> 4) * 8u + j;
    float val = 0.f;
    if ((vp < 1000u) & (up < 1000u)) {
      const uint32_t flat = (tk * 1000u + up) * 1000u + vp;
      uint32_t o0, o1;
      threefry2x32(0u, flat, o0, o1);
      const uint32_t bits = o0 ^ o1;
      const float u = __uint_as_float((bits >> 9) | 0x3f800000u) - 1.0f;
      if (u < 0.4f) {
        val = cheb[(tk % 3u) * 1000000u + up * 1000u + vp] *
              Att[up * 1000u + vp] * 2.5f;
      }
    }
    Mf[idx] = f2bf(val);
    return;
  }

  // ---- transpose role: xt[t][n=b*64+f][v pad 1024] <- x[b][t][v][f] ----
  const int r = bid;
  const int vc = r & 15, t = (r >> 4) % 12, b = r / 192;
  const int v0 = vc * 64;
#pragma unroll
  for (int i = 0; i < 4; ++i) {
    const int c = i * 256 + tid;
    const int vi = c >> 4, f4 = c & 15;
    float4 q = make_float4(0.f, 0.f, 0.f, 0.f);
    if (v0 + vi < 1000)
      q = *(const float4*)(x + ((((size_t)b * 12 + t) * 1000 + v0 + vi) << 6) + f4 * 4);
    lt[f4 * 4 + 0][vi] = q.x;
    lt[f4 * 4 + 1][vi] = q.y;
    lt[f4 * 4 + 2][vi] = q.z;
    lt[f4 * 4 + 3][vi] = q.w;
  }
  __syncthreads();
  const int f = tid >> 2, g = tid & 3;
  alignas(16) ushort tmp[16];
#pragma unroll
  for (int j = 0; j < 16; ++j) tmp[j] = f2bf(lt[f][g * 16 + j]);
  const size_t base = ((size_t)(t * 2048 + b * 64 + f)) << 10;
  *(uint4*)(xtw + base + v0 + g * 16)     = *(const uint4*)&tmp[0];
  *(uint4*)(xtw + base + v0 + g * 16 + 8) = *(const uint4*)&tmp[8];
}

// ---------------------------------------------------------------------------
// Kernel 2: main fused GEMM, hybrid operand paths (R19/R22/R24-verified).
// 256 thr (4 waves, 2x2), block 64u x 128n per t, wave tile 32u x 64n.
// Per 64-chunk: A = 12 frag loads direct from Mf (coalesced 1KB, L2-hot);
// B = LDS dbuf (2x16KB, one barrier/chunk, issue-early reg prefetch,
// XOR content swizzle). 48 MFMA into pacc[3] (AGPR).
// Stage 2 (k unrolled): pacc[k] -> sP -> oacc += P @ ThetaT[k].
// Epilogue: relu + nontemporal f32 store (timing-neutral, measured).
// Grid 3072 1D, XCD-bijective, ut-fastest (A panels L2-hot per XCD).
// ---------------------------------------------------------------------------
#define LDT 72
#define MFMA(a, b, c) __builtin_amdgcn_mfma_f32_16x16x32_bf16((a), (b), (c), 0, 0, 0)

#define LOADB(VC)                                                             \
  do {                                                                        \
    const size_t co_ = (size_t)(VC) * 64;                                     \
    p6 = *(const uint4*)(xt + bS0 + co_);                                     \
    p7 = *(const uint4*)(xt + bS1 + co_);                                     \
    p8 = *(const uint4*)(xt + bS2 + co_);                                     \
    p9 = *(const uint4*)(xt + bS3 + co_);                                     \
  } while (0)

#define WRITEB(BP)                                                            \
  do {                                                                        \
    *(uint4*)&(BP)[(tid) * 8]        = p6;                                    \
    *(uint4*)&(BP)[(256 + tid) * 8]  = p7;                                    \
    *(uint4*)&(BP)[(512 + tid) * 8]  = p8;                                    \
    *(uint4*)&(BP)[(768 + tid) * 8]  = p9;                                    \
  } while (0)

#define LOADA(VC)                                                             \
  do {                                                                        \
    const size_t co_ = (size_t)(VC) << 10;                                    \
    _Pragma("unroll")                                                         \
    for (int k = 0; k < 3; ++k)                                               \
      _Pragma("unroll")                                                       \
      for (int mi = 0; mi < 2; ++mi)                                          \
        _Pragma("unroll")                                                     \
        for (int ks = 0; ks < 2; ++ks)                                        \
          a[k][mi][ks] = *(const short8*)(Mf + fA[k][mi] + co_ +              \
                                          ((size_t)ks << 9));                 \
  } while (0)

#define BURST(BP)                                                             \
  do {                                                                        \
    _Pragma("unroll")                                                         \
    for (int ks = 0; ks < 2; ++ks) {                                          \
      const int cs_ = (((ks * 4 + quad) ^ rsw)) << 3;                         \
      short8 bv[4];                                                           \
      _Pragma("unroll")                                                       \
      for (int ni = 0; ni < 4; ++ni)                                          \
        bv[ni] = *(const short8*)&(BP)[(wn * 64 + ni * 16 + l15) * 64 + cs_]; \
      _Pragma("unroll")                                                       \
      for (int k = 0; k < 3; ++k)                                             \
        _Pragma("unroll")                                                     \
        for (int mi = 0; mi < 2; ++mi)                                        \
          _Pragma("unroll")                                                   \
          for (int ni = 0; ni < 4; ++ni)                                      \
            pacc[k][mi][ni] = MFMA(a[k][mi][ks], bv[ni], pacc[k][mi][ni]);    \
    }                                                                         \
  } while (0)

__global__ __launch_bounds__(256, 2)
void cheb_main(const ushort* __restrict__ Mf, const ushort* __restrict__ xt,
               const float* __restrict__ Theta, float* __restrict__ out) {
  __shared__ __align__(16) ushort smem[16384];  // 32KB: B buf0 | buf1
  const int tid = threadIdx.x;
  const int lane = tid & 63;
  const int w = tid >> 6;              // wave 0..3
  const int wu = w >> 1, wn = w & 1;   // wave tile: u = wu*32, n = wn*64
  const int quad = lane >> 4, l15 = lane & 15;
  const int rsw = l15 & 7;

  ushort* buf0 = smem;
  ushort* buf1 = smem + 8192;

  // XCD-bijective decode (3072 % 8 == 0), ut-fastest within each XCD chunk
  const int bid = blockIdx.x;
  const int swz = (bid & 7) * 384 + (bid >> 3);
  const int ut = swz & 15;
  const int g = swz >> 4;              // 0..191
  const int nt = g & 15;
  const int t = g >> 4;                // 0..11
  const int u0 = ut * 64, n0 = nt * 128;

  // A fragment bases (frag-order Mf): u16 = ut*4 + wu*2 + mi
  size_t fA[3][2];
#pragma unroll
  for (int k = 0; k < 3; ++k)
#pragma unroll
    for (int mi = 0; mi < 2; ++mi)
      fA[k][mi] = (((size_t)((t * 3 + k) * 64 + ut * 4 + wu * 2 + mi)) << 14)
                  + (size_t)lane * 8;

  // B staging sources (xt row-major, XOR content pre-swizzle) -- verified
  const size_t xrow0 = (size_t)(t * 2048 + n0);
  const int rB0 = tid >> 3,         cB0 = (tid & 7) ^ (rB0 & 7);
  const int rB1 = (256 + tid) >> 3, cB1 = (tid & 7) ^ (rB1 & 7);
  const int rB2 = (512 + tid) >> 3, cB2 = (tid & 7) ^ (rB2 & 7);
  const int rB3 = (768 + tid) >> 3, cB3 = (tid & 7) ^ (rB3 & 7);
  const size_t bS0 = ((xrow0 + rB0) << 10) + cB0 * 8;
  const size_t bS1 = ((xrow0 + rB1) << 10) + cB1 * 8;
  const size_t bS2 = ((xrow0 + rB2) << 10) + cB2 * 8;
  const size_t bS3 = ((xrow0 + rB3) << 10) + cB3 * 8;

  f32x4 pacc[3][2][4];
#pragma unroll
  for (int k = 0; k < 3; ++k)
#pragma unroll
    for (int i = 0; i < 2; ++i)
#pragma unroll
      for (int j = 0; j < 4; ++j) pacc[k][i][j] = f32x4{0.f, 0.f, 0.f, 0.f};

  short8 a[3][2][2];
  uint4 p6, p7, p8, p9;

  // prologue: B chunk 0 -> buf0
  LOADB(0);
  WRITEB(buf0);
  __syncthreads();

  // main K loop: 16 chunks, unrolled x2 for static buffer pointers;
  // one barrier per chunk (write targets buffer read last iteration)
#pragma unroll 1
  for (int it = 0; it < 8; ++it) {
    const int vc = it * 2;
    // even chunk: read buf0; prefetch B(vc+1) regs; A(vc) direct
    if (vc < 15) LOADB(vc + 1);
    LOADA(vc);
    __builtin_amdgcn_s_setprio(1);
    BURST(buf0);
    __builtin_amdgcn_s_setprio(0);
    if (vc < 15) WRITEB(buf1);
    __syncthreads();
    // odd chunk: read buf1; prefetch B(vc+2); A(vc+1)
    if (vc + 1 < 15) LOADB(vc + 2);
    LOADA(vc + 1);
    __builtin_amdgcn_s_setprio(1);
    BURST(buf1);
    __builtin_amdgcn_s_setprio(0);
    if (vc + 1 < 15) WRITEB(buf0);
    __syncthreads();
  }

  // ---- stage 2: oacc += P_k @ ThetaT[k], k fully unrolled ----
  ushort* sP  = smem + w * 2304;       // 32 x 72, wave-local
  ushort* sTh = smem + 9216;           // 64 x 72  (9216+4608 = 13824 <= 16384)
  f32x4 oacc[2][4];
#pragma unroll
  for (int i = 0; i < 2; ++i)
#pragma unroll
    for (int j = 0; j < 4; ++j) oacc[i][j] = f32x4{0.f, 0.f, 0.f, 0.f};

#pragma unroll
  for (int k = 0; k < 3; ++k) {
    __syncthreads();  // prev readers done
#pragma unroll
    for (int mi = 0; mi < 2; ++mi)
#pragma unroll
      for (int ni = 0; ni < 4; ++ni)
#pragma unroll
        for (int r = 0; r < 4; ++r)
          sP[(mi * 16 + quad * 4 + r) * LDT + ni * 16 + l15] = f2bf(pacc[k][mi][ni][r]);
    for (int e = tid; e < 4096; e += 256) {
      const int f = e >> 6, o = e & 63;
      sTh[o * LDT + f] = f2bf(Theta[k * 4096 + e]);
    }
    __syncthreads();
#pragma unroll
    for (int ks = 0; ks < 2; ++ks) {
      short8 a2[2], b2[4];
#pragma unroll
      for (int mi = 0; mi < 2; ++mi)
        a2[mi] = *(const short8*)&sP[(mi * 16 + l15) * LDT + ks * 32 + quad * 8];
#pragma unroll
      for (int ni = 0; ni < 4; ++ni)
        b2[ni] = *(const short8*)&sTh[(ni * 16 + l15) * LDT + ks * 32 + quad * 8];
#pragma unroll
      for (int mi = 0; mi < 2; ++mi)
#pragma unroll
        for (int ni = 0; ni < 4; ++ni)
          oacc[mi][ni] = MFMA(a2[mi], b2[ni], oacc[mi][ni]);
    }
  }

  // ---- epilogue: relu + nontemporal f32 store (out never re-read) ----
#pragma unroll
  for (int mi = 0; mi < 2; ++mi) {
    const int u_base = u0 + wu * 32 + mi * 16 + quad * 4;
#pragma unroll
    for (int ni = 0; ni < 4; ++ni) {
      const int n = n0 + wn * 64 + ni * 16 + l15;
      const int b = n >> 6, oo = n & 63;
      float* op = out + (((size_t)b * 12 + t) * 1000) * 64 + oo;
#pragma unroll
      for (int r = 0; r < 4; ++r) {
        const int u = u_base + r;
        if (u < 1000)
          __builtin_nontemporal_store(fmaxf(oacc[mi][ni][r], 0.f),
                                      op + (size_t)u * 64);
      }
    }
  }
}

// ---------------------------------------------------------------------------
extern "C" void kernel_launch(void* const* d_in, const int* in_sizes, int n_in,
                              void* d_out, int out_size, void* d_ws, size_t ws_size,
                              hipStream_t stream) {
  const float* x     = (const float*)d_in[0];
  const float* Att   = (const float*)d_in[1];
  const float* cheb  = (const float*)d_in[2];
  const float* Theta = (const float*)d_in[3];
  float* out = (float*)d_out;

  ushort* Mf  = (ushort*)d_ws;                 // 36*1024*1024 bf16, frag order
  ushort* xtw = Mf + 37748736ull;              // 12*2048*1024 bf16 row-major
  // requires ws_size >= 125,829,120 bytes (proven budget)

  prep<<<153600, 256, 0, stream>>>(x, Att, cheb, Mf, xtw);
  cheb_main<<<3072, 256, 0, stream>>>(Mf, xtw, Theta, out);
}